// Round 1
// baseline (595.360 us; speedup 1.0000x reference)
//
#include <hip/hip_runtime.h>
#include <hip/hip_bf16.h>
#include <math.h>

// Problem constants (B=8, L=4096, D=512, P=128, 4 scales, O=512)
#define BATCH 8
#define SEQL  4096
#define DIM   512
#define FEAT  512   // 4 scales * P=128
#define OUTD  512

// ---------------- SGEMM: C[M,N] = A[M,K] * B[N,K]^T (+bias) ----------------
#define BM 128
#define BN 128
#define BK 16
#define TM 8
#define TN 8

__global__ __launch_bounds__(256)
void sgemm_bt(const float* __restrict__ A, const float* __restrict__ B,
              const float* __restrict__ bias, float* __restrict__ C,
              int M, int N, int K)
{
    __shared__ float As[BK][BM + 4];
    __shared__ float Bs[BK][BN + 4];
    const int tid = threadIdx.x;
    const int tx = tid & 15;        // 0..15 -> N direction
    const int ty = tid >> 4;        // 0..15 -> M direction
    const int arow0 = blockIdx.y * BM;
    const int bcol0 = blockIdx.x * BN;

    float acc[TM][TN];
#pragma unroll
    for (int m = 0; m < TM; ++m)
#pragma unroll
        for (int n = 0; n < TN; ++n) acc[m][n] = 0.f;

    for (int k0 = 0; k0 < K; k0 += BK) {
        // stage A,B tiles (transposed into LDS): 128x16 each, float4 loads
#pragma unroll
        for (int it = 0; it < 2; ++it) {
            const int ff  = tid + it * 256;   // 0..511
            const int row = ff >> 2;          // 0..127
            const int kc  = (ff & 3) << 2;    // 0,4,8,12
            const float4 av = *(const float4*)&A[(size_t)(arow0 + row) * K + k0 + kc];
            As[kc + 0][row] = av.x; As[kc + 1][row] = av.y;
            As[kc + 2][row] = av.z; As[kc + 3][row] = av.w;
            const float4 bv = *(const float4*)&B[(size_t)(bcol0 + row) * K + k0 + kc];
            Bs[kc + 0][row] = bv.x; Bs[kc + 1][row] = bv.y;
            Bs[kc + 2][row] = bv.z; Bs[kc + 3][row] = bv.w;
        }
        __syncthreads();
#pragma unroll
        for (int k = 0; k < BK; ++k) {
            float a[TM], b[TN];
#pragma unroll
            for (int m = 0; m < TM; ++m) a[m] = As[k][ty * TM + m];
#pragma unroll
            for (int n = 0; n < TN; ++n) b[n] = Bs[k][tx * TN + n];
#pragma unroll
            for (int m = 0; m < TM; ++m)
#pragma unroll
                for (int n = 0; n < TN; ++n) acc[m][n] += a[m] * b[n];
        }
        __syncthreads();
    }

    // epilogue
#pragma unroll
    for (int m = 0; m < TM; ++m) {
        const size_t crow = (size_t)(arow0 + ty * TM + m) * N + bcol0 + tx * TN;
#pragma unroll
        for (int n4 = 0; n4 < TN; n4 += 4) {
            float4 v = make_float4(acc[m][n4 + 0], acc[m][n4 + 1],
                                   acc[m][n4 + 2], acc[m][n4 + 3]);
            if (bias) {
                const int c = bcol0 + tx * TN + n4;
                v.x += bias[c + 0]; v.y += bias[c + 1];
                v.z += bias[c + 2]; v.w += bias[c + 3];
            }
            *(float4*)&C[crow + n4] = v;
        }
    }
}

// ------------- causal window-mean (running sum) + bias + exact GELU -------------
// U:(B,L,512) -> Cat:(B,L,512). Feature j's scale group = j>>7 (P=128).
// grid: (L/CHUNK, 8 feature-groups of 64, B), block: 64 (one wave).
#define CHUNK 128

__device__ __forceinline__ float gelu_exact(float h) {
    return 0.5f * h * (1.f + erff(h * 0.70710678118654752f));
}

__global__ __launch_bounds__(64)
void pool_gelu(const float* __restrict__ U, const float* __restrict__ bsv,
               float* __restrict__ Cat)
{
    const int lane = threadIdx.x;          // 0..63
    const int jg   = blockIdx.y;           // 0..7
    const int b    = blockIdx.z;           // 0..7
    const int j    = jg * 64 + lane;       // 0..511
    const int si   = j >> 7;               // scale index (wave-uniform)
    const int n    = (si == 0) ? 1 : (si == 1) ? 5 : (si == 2) ? 32 : 128;
    const int l0   = blockIdx.x * CHUNK;

    const float* Ub = U   + (size_t)b * SEQL * FEAT + j;
    float*       Cb = Cat + (size_t)b * SEQL * FEAT + j;
    const float bias = bsv[j];

    if (n == 1) {  // identity pooling
#pragma unroll 4
        for (int l = l0; l < l0 + CHUNK; ++l) {
            const float h = Ub[(size_t)l * FEAT] + bias;
            Cb[(size_t)l * FEAT] = gelu_exact(h);
        }
        return;
    }

    // lead-in: s = sum over [max(0,l0-n), l0)
    float s = 0.f;
    for (int k = l0 - min(n, l0); k < l0; ++k) s += Ub[(size_t)k * FEAT];

    if (l0 >= n) {  // steady state: full window, constant denom
        const float rinv = 1.f / (float)n;
#pragma unroll 4
        for (int l = l0; l < l0 + CHUNK; ++l) {
            s += Ub[(size_t)l * FEAT];
            s -= Ub[(size_t)(l - n) * FEAT];
            Cb[(size_t)l * FEAT] = gelu_exact(s * rinv + bias);
        }
    } else {        // ramp (only block l0==0 since n <= CHUNK)
        for (int l = l0; l < l0 + CHUNK; ++l) {
            s += Ub[(size_t)l * FEAT];
            if (l >= n) s -= Ub[(size_t)(l - n) * FEAT];
            const float d = (float)min(l + 1, n);
            Cb[(size_t)l * FEAT] = gelu_exact(s / d + bias);
        }
    }
}

// ---------------------------------------------------------------------------
extern "C" void kernel_launch(void* const* d_in, const int* in_sizes, int n_in,
                              void* d_out, int out_size, void* d_ws, size_t ws_size,
                              hipStream_t stream)
{
    const float* x  = (const float*)d_in[0];  // (B,L,D)
    const float* Ws = (const float*)d_in[1];  // (4,128,512) == (512,512) row-major
    const float* bs = (const float*)d_in[2];  // (512)
    const float* Wc = (const float*)d_in[3];  // (512,512)
    const float* bc = (const float*)d_in[4];  // (512)
    float* out = (float*)d_out;

    const int M = BATCH * SEQL;               // 32768

    float* U   = out;                          // reuse d_out as scratch for U
    float* cat = (float*)d_ws;                 // 64 MB in workspace

    // 1) U = x @ Ws_all^T   (pooling commutes with the per-scale Linear)
    sgemm_bt<<<dim3(FEAT / BN, M / BM), 256, 0, stream>>>(x, Ws, nullptr, U, M, FEAT, DIM);

    // 2) causal window-mean in feature space + bias + exact GELU
    pool_gelu<<<dim3(SEQL / CHUNK, 8, BATCH), 64, 0, stream>>>(U, bs, cat);

    // 3) out = cat @ Wc^T + bc
    sgemm_bt<<<dim3(OUTD / BN, M / BM), 256, 0, stream>>>(cat, Wc, bc, out, M, OUTD, FEAT);
}

// Round 2
// 249.605 us; speedup vs baseline: 2.3852x; 2.3852x over previous
//
#include <hip/hip_runtime.h>
#include <hip/hip_bf16.h>
#include <math.h>

// B=8, L=4096, D=512, P=128, 4 scales, O=512. M = B*L = 32768.
#define BATCH 8
#define SEQL  4096
#define DIM   512
#define FEAT  512
#define OUTD  512

typedef __attribute__((ext_vector_type(8))) short short8_t;  // 8 bf16 (4 VGPRs)
typedef __attribute__((ext_vector_type(4))) float f32x4;

__device__ __forceinline__ short bfbits(float f) {
    __hip_bfloat16 h = __float2bfloat16(f);
    return __builtin_bit_cast(short, h);
}

__device__ __forceinline__ short8_t pack8(float4 a, float4 b) {
    short8_t r;
    r[0] = bfbits(a.x); r[1] = bfbits(a.y); r[2] = bfbits(a.z); r[3] = bfbits(a.w);
    r[4] = bfbits(b.x); r[5] = bfbits(b.y); r[6] = bfbits(b.z); r[7] = bfbits(b.w);
    return r;
}

// ---------------- bf16 MFMA GEMM: C[M,N] = A[M,K] * B[N,K]^T (+bias) ----------------
// 128x128 tile, BK=32, 4 waves (2x2), each wave 64x64 via 4x4 frags of 16x16x32.
// A: fp32 (converted while staging) or bf16 (direct). B: always fp32 source.
// LDS rows padded to 40 elems (80B) -> frag ds_read_b128 ~2-way banks (free).
#define LDK 40

template<bool AF32, bool HASBIAS>
__global__ __launch_bounds__(256)
void mfma_gemm(const void* __restrict__ A, const float* __restrict__ Bw,
               const float* __restrict__ bias, float* __restrict__ C,
               int M, int N, int K)
{
    __shared__ short As[128 * LDK];
    __shared__ short Bs[128 * LDK];

    const int tid  = threadIdx.x;
    const int lane = tid & 63;
    const int wave = tid >> 6;            // 0..3
    const int wr   = wave >> 1;           // 0..1 (M)
    const int wc   = wave & 1;            // 0..1 (N)
    const int fr   = lane & 15;           // frag row (A) / col (B)
    const int kb   = lane >> 4;           // k-chunk of 8

    const int arow0 = blockIdx.y * 128;
    const int bcol0 = blockIdx.x * 128;

    const int srow = tid >> 1;            // staging row 0..127
    const int shalf = tid & 1;            // 16-elem half of BK=32

    f32x4 acc[4][4];
#pragma unroll
    for (int m = 0; m < 4; ++m)
#pragma unroll
        for (int n = 0; n < 4; ++n) acc[m][n] = (f32x4)0.f;

    for (int k0 = 0; k0 < K; k0 += 32) {
        // ---- stage A tile (128x32 bf16) ----
        if (AF32) {
            const float* ag = ((const float*)A) + (size_t)(arow0 + srow) * K + k0 + shalf * 16;
            float4 f0 = *(const float4*)(ag + 0);
            float4 f1 = *(const float4*)(ag + 4);
            float4 f2 = *(const float4*)(ag + 8);
            float4 f3 = *(const float4*)(ag + 12);
            *(short8_t*)&As[srow * LDK + shalf * 16 + 0] = pack8(f0, f1);
            *(short8_t*)&As[srow * LDK + shalf * 16 + 8] = pack8(f2, f3);
        } else {
            const short8_t* ag = (const short8_t*)(((const unsigned short*)A)
                                 + (size_t)(arow0 + srow) * K + k0 + shalf * 16);
            *(short8_t*)&As[srow * LDK + shalf * 16 + 0] = ag[0];
            *(short8_t*)&As[srow * LDK + shalf * 16 + 8] = ag[1];
        }
        // ---- stage B tile (128x32 bf16, from fp32 weights) ----
        {
            const float* bg = Bw + (size_t)(bcol0 + srow) * K + k0 + shalf * 16;
            float4 f0 = *(const float4*)(bg + 0);
            float4 f1 = *(const float4*)(bg + 4);
            float4 f2 = *(const float4*)(bg + 8);
            float4 f3 = *(const float4*)(bg + 12);
            *(short8_t*)&Bs[srow * LDK + shalf * 16 + 0] = pack8(f0, f1);
            *(short8_t*)&Bs[srow * LDK + shalf * 16 + 8] = pack8(f2, f3);
        }
        __syncthreads();

        short8_t af[4], bfr[4];
#pragma unroll
        for (int m = 0; m < 4; ++m)
            af[m] = *(const short8_t*)&As[(wr * 64 + m * 16 + fr) * LDK + kb * 8];
#pragma unroll
        for (int n = 0; n < 4; ++n)
            bfr[n] = *(const short8_t*)&Bs[(wc * 64 + n * 16 + fr) * LDK + kb * 8];
#pragma unroll
        for (int m = 0; m < 4; ++m)
#pragma unroll
            for (int n = 0; n < 4; ++n)
                acc[m][n] = __builtin_amdgcn_mfma_f32_16x16x32_bf16(af[m], bfr[n], acc[m][n], 0, 0, 0);
        __syncthreads();
    }

    // ---- epilogue: C/D layout col=lane&15, row=(lane>>4)*4+i ----
#pragma unroll
    for (int n = 0; n < 4; ++n) {
        const int col = bcol0 + wc * 64 + n * 16 + fr;
        const float bv = HASBIAS ? bias[col] : 0.f;
#pragma unroll
        for (int m = 0; m < 4; ++m) {
            const size_t row0 = (size_t)(arow0 + wr * 64 + m * 16 + kb * 4);
#pragma unroll
            for (int i = 0; i < 4; ++i)
                C[(row0 + i) * N + col] = acc[m][n][i] + bv;
        }
    }
}

// ------------- causal window-mean + bias + exact GELU, writes bf16 -------------
// U:(B,L,512) fp32 -> Cat:(B,L,512) bf16. Scale group = j>>7 (P=128), n={1,5,32,128}.
// 512 threads/block (8 waves, wave-uniform scale), grid (L/64, B) -> 16 waves/CU.
#define PCHUNK 64

__device__ __forceinline__ float gelu_exact(float h) {
    return 0.5f * h * (1.f + erff(h * 0.70710678118654752f));
}

__global__ __launch_bounds__(512)
void pool_gelu(const float* __restrict__ U, const float* __restrict__ bsv,
               __hip_bfloat16* __restrict__ Cat)
{
    const int j  = threadIdx.x;            // 0..511
    const int si = j >> 7;
    const int n  = (si == 0) ? 1 : (si == 1) ? 5 : (si == 2) ? 32 : 128;
    const int b  = blockIdx.y;
    const int l0 = blockIdx.x * PCHUNK;

    const float* Ub = U + (size_t)b * SEQL * FEAT + j;
    __hip_bfloat16* Cb = Cat + (size_t)b * SEQL * FEAT + j;
    const float bias = bsv[j];

    if (n == 1) {
#pragma unroll 8
        for (int l = l0; l < l0 + PCHUNK; ++l)
            Cb[(size_t)l * FEAT] = __float2bfloat16(gelu_exact(Ub[(size_t)l * FEAT] + bias));
        return;
    }

    // lead-in: s = sum over [max(0,l0-n), l0), 4 accumulators for ILP
    float s;
    {
        const int kstart = l0 - min(n, l0);
        float s0 = 0.f, s1 = 0.f, s2 = 0.f, s3 = 0.f;
        int k = kstart;
        for (; k + 4 <= l0; k += 4) {
            s0 += Ub[(size_t)(k + 0) * FEAT];
            s1 += Ub[(size_t)(k + 1) * FEAT];
            s2 += Ub[(size_t)(k + 2) * FEAT];
            s3 += Ub[(size_t)(k + 3) * FEAT];
        }
        for (; k < l0; ++k) s0 += Ub[(size_t)k * FEAT];
        s = (s0 + s1) + (s2 + s3);
    }

    if (l0 >= n) {  // steady state
        const float rinv = 1.f / (float)n;
#pragma unroll 8
        for (int l = l0; l < l0 + PCHUNK; ++l) {
            s += Ub[(size_t)l * FEAT];
            s -= Ub[(size_t)(l - n) * FEAT];
            Cb[(size_t)l * FEAT] = __float2bfloat16(gelu_exact(s * rinv + bias));
        }
    } else {        // ramp (l0 < n): denom = min(l+1, n)
        for (int l = l0; l < l0 + PCHUNK; ++l) {
            s += Ub[(size_t)l * FEAT];
            if (l >= n) s -= Ub[(size_t)(l - n) * FEAT];
            const float d = (float)min(l + 1, n);
            Cb[(size_t)l * FEAT] = __float2bfloat16(gelu_exact(s / d + bias));
        }
    }
}

// ---------------------------------------------------------------------------
extern "C" void kernel_launch(void* const* d_in, const int* in_sizes, int n_in,
                              void* d_out, int out_size, void* d_ws, size_t ws_size,
                              hipStream_t stream)
{
    const float* x  = (const float*)d_in[0];  // (B,L,512) fp32
    const float* Ws = (const float*)d_in[1];  // (512,512) fp32, K contiguous
    const float* bs = (const float*)d_in[2];  // (512)
    const float* Wc = (const float*)d_in[3];  // (512,512) fp32
    const float* bc = (const float*)d_in[4];  // (512)
    float* out = (float*)d_out;

    const int M = BATCH * SEQL;               // 32768

    float* U = out;                            // fp32 scratch in d_out (overwritten by GEMM2)
    __hip_bfloat16* cat = (__hip_bfloat16*)d_ws;  // 32 MB bf16 in workspace

    // 1) U = bf16(x) @ bf16(Ws)^T  (pooling commutes with per-scale Linear)
    mfma_gemm<true, false><<<dim3(FEAT / 128, M / 128), 256, 0, stream>>>(
        x, Ws, nullptr, U, M, FEAT, DIM);

    // 2) causal window-mean in feature space + bias + exact GELU -> bf16 cat
    pool_gelu<<<dim3(SEQL / PCHUNK, BATCH), 512, 0, stream>>>(U, bs, cat);

    // 3) out = cat @ bf16(Wc)^T + bc
    mfma_gemm<false, true><<<dim3(OUTD / 128, M / 128), 256, 0, stream>>>(
        cat, Wc, bc, out, M, OUTD, FEAT);
}

// Round 3
// 244.493 us; speedup vs baseline: 2.4351x; 1.0209x over previous
//
#include <hip/hip_runtime.h>
#include <hip/hip_bf16.h>
#include <math.h>

// B=8, L=4096, D=512, P=128 (4 scales), O=512. M = B*L = 32768.
#define BATCH 8
#define SEQL  4096
#define DIM   512
#define FEAT  512
#define OUTD  512

typedef __attribute__((ext_vector_type(8))) short short8_t;  // 8 bf16
typedef __attribute__((ext_vector_type(4))) float f32x4;

__device__ __forceinline__ short bfbits(float f) {
    __hip_bfloat16 h = __float2bfloat16(f);
    return __builtin_bit_cast(short, h);
}
__device__ __forceinline__ short8_t pack8(float4 a, float4 b) {
    short8_t r;
    r[0] = bfbits(a.x); r[1] = bfbits(a.y); r[2] = bfbits(a.z); r[3] = bfbits(a.w);
    r[4] = bfbits(b.x); r[5] = bfbits(b.y); r[6] = bfbits(b.z); r[7] = bfbits(b.w);
    return r;
}

// async global->LDS, 16B per lane (wave-uniform LDS base + lane*16)
__device__ __forceinline__ void gload_lds16(const unsigned short* g, unsigned short* l) {
    __builtin_amdgcn_global_load_lds(
        (const __attribute__((address_space(1))) unsigned int*)g,
        (__attribute__((address_space(3))) unsigned int*)l,
        16, 0, 0);
}

// ---------------- fp32 -> bf16 convert (x only; 16 elems/thread) ----------------
__global__ __launch_bounds__(256)
void cvt_bf16(const float* __restrict__ src, unsigned short* __restrict__ dst)
{
    const size_t i = (size_t)blockIdx.x * 256 + threadIdx.x;
    const float4* s = (const float4*)src + i * 4;
    float4 f0 = s[0], f1 = s[1], f2 = s[2], f3 = s[3];
    short8_t* d = (short8_t*)dst + i * 2;
    d[0] = pack8(f0, f1);
    d[1] = pack8(f2, f3);
}

// ------------- bf16 MFMA GEMM (m97 structure): C[M,N] = A[M,K]*B[N,K]^T (+bias) ----
// 128x128 tile, BK=32, 4 waves (2x2), wave = 64x64 = 4x4 frags of 16x16x32.
// A: bf16, staged via global_load_lds dwordx4 (linear LDS [128][32]).
// B: fp32 weights, reg-staged with fused fp32->bf16 pack (1 MB, L2-resident).
// Grid is 1D with bijective XCD-chunk swizzle (nwg % 8 == 0).
template<bool HASBIAS>
__global__ __launch_bounds__(256)
void mfma_gemm(const unsigned short* __restrict__ A, const float* __restrict__ Bw,
               const float* __restrict__ bias, float* __restrict__ C,
               int M, int N, int K, int nbx)
{
    __shared__ unsigned short As[128 * 32];
    __shared__ unsigned short Bs[128 * 32];

    // XCD-chunk swizzle: XCD x gets original blocks [x*cpx, (x+1)*cpx)
    const int cpx  = gridDim.x >> 3;
    const int orig = (blockIdx.x & 7) * cpx + (blockIdx.x >> 3);
    const int by = orig / nbx;
    const int bx = orig % nbx;

    const int tid  = threadIdx.x;
    const int lane = tid & 63;
    const int wave = tid >> 6;
    const int wr = wave >> 1, wc = wave & 1;
    const int fr = lane & 15, kb = lane >> 4;

    const int arow0 = by * 128;
    const int bcol0 = bx * 128;

    // A staging: thread covers LDS bytes [tid*16, +16) (+4096 for r=1)
    const int s_arow = tid >> 2;          // 0..63
    const int s_acol = (tid & 3) * 8;     // elem col in BK=32
    // B staging: thread converts 16 fp32 -> 16 bf16
    const int s_brow = tid >> 1;          // 0..127
    const int s_bcol = (tid & 1) * 16;

    f32x4 acc[4][4];
#pragma unroll
    for (int m = 0; m < 4; ++m)
#pragma unroll
        for (int n = 0; n < 4; ++n) acc[m][n] = (f32x4)0.f;

    for (int k0 = 0; k0 < K; k0 += 32) {
        // ---- A tile via async global->LDS (2 x 16B per thread) ----
        gload_lds16(A + (size_t)(arow0 + s_arow) * K + k0 + s_acol, &As[tid * 8]);
        gload_lds16(A + (size_t)(arow0 + 64 + s_arow) * K + k0 + s_acol, &As[tid * 8 + 2048]);
        // ---- B tile reg-staged (fp32 -> bf16) ----
        {
            const float* bg = Bw + (size_t)(bcol0 + s_brow) * K + k0 + s_bcol;
            float4 f0 = *(const float4*)(bg + 0);
            float4 f1 = *(const float4*)(bg + 4);
            float4 f2 = *(const float4*)(bg + 8);
            float4 f3 = *(const float4*)(bg + 12);
            *(short8_t*)&Bs[s_brow * 32 + s_bcol + 0] = pack8(f0, f1);
            *(short8_t*)&Bs[s_brow * 32 + s_bcol + 8] = pack8(f2, f3);
        }
        __syncthreads();   // drains vmcnt (gload_lds) + lgkmcnt (ds_write)

        short8_t af[4], bf_[4];
#pragma unroll
        for (int m = 0; m < 4; ++m)
            af[m] = *(const short8_t*)&As[(wr * 64 + m * 16 + fr) * 32 + kb * 8];
#pragma unroll
        for (int n = 0; n < 4; ++n)
            bf_[n] = *(const short8_t*)&Bs[(wc * 64 + n * 16 + fr) * 32 + kb * 8];
#pragma unroll
        for (int m = 0; m < 4; ++m)
#pragma unroll
            for (int n = 0; n < 4; ++n)
                acc[m][n] = __builtin_amdgcn_mfma_f32_16x16x32_bf16(af[m], bf_[n], acc[m][n], 0, 0, 0);
        __syncthreads();
    }

    // epilogue: C/D layout col=lane&15, row=(lane>>4)*4+i
#pragma unroll
    for (int n = 0; n < 4; ++n) {
        const int col = bcol0 + wc * 64 + n * 16 + fr;
        const float bv = HASBIAS ? bias[col] : 0.f;
#pragma unroll
        for (int m = 0; m < 4; ++m) {
            const size_t row0 = (size_t)(arow0 + wr * 64 + m * 16 + kb * 4);
#pragma unroll
            for (int i = 0; i < 4; ++i)
                C[(row0 + i) * N + col] = acc[m][n][i] + bv;
        }
    }
}

// ------------- causal window-mean + bias + exact GELU, fp32 U -> bf16 cat -------------
#define PCHUNK 64

__device__ __forceinline__ float gelu_exact(float h) {
    return 0.5f * h * (1.f + erff(h * 0.70710678118654752f));
}

__global__ __launch_bounds__(512)
void pool_gelu(const float* __restrict__ U, const float* __restrict__ bsv,
               __hip_bfloat16* __restrict__ Cat)
{
    const int j  = threadIdx.x;            // 0..511
    const int si = j >> 7;
    const int n  = (si == 0) ? 1 : (si == 1) ? 5 : (si == 2) ? 32 : 128;
    const int b  = blockIdx.y;
    const int l0 = blockIdx.x * PCHUNK;

    const float* Ub = U + (size_t)b * SEQL * FEAT + j;
    __hip_bfloat16* Cb = Cat + (size_t)b * SEQL * FEAT + j;
    const float bias = bsv[j];

    if (n == 1) {
#pragma unroll 8
        for (int l = l0; l < l0 + PCHUNK; ++l)
            Cb[(size_t)l * FEAT] = __float2bfloat16(gelu_exact(Ub[(size_t)l * FEAT] + bias));
        return;
    }

    float s;
    {
        const int kstart = l0 - min(n, l0);
        float s0 = 0.f, s1 = 0.f, s2 = 0.f, s3 = 0.f;
        int k = kstart;
        for (; k + 4 <= l0; k += 4) {
            s0 += Ub[(size_t)(k + 0) * FEAT];
            s1 += Ub[(size_t)(k + 1) * FEAT];
            s2 += Ub[(size_t)(k + 2) * FEAT];
            s3 += Ub[(size_t)(k + 3) * FEAT];
        }
        for (; k < l0; ++k) s0 += Ub[(size_t)k * FEAT];
        s = (s0 + s1) + (s2 + s3);
    }

    if (l0 >= n) {
        const float rinv = 1.f / (float)n;
#pragma unroll 8
        for (int l = l0; l < l0 + PCHUNK; ++l) {
            s += Ub[(size_t)l * FEAT];
            s -= Ub[(size_t)(l - n) * FEAT];
            Cb[(size_t)l * FEAT] = __float2bfloat16(gelu_exact(s * rinv + bias));
        }
    } else {
        for (int l = l0; l < l0 + PCHUNK; ++l) {
            s += Ub[(size_t)l * FEAT];
            if (l >= n) s -= Ub[(size_t)(l - n) * FEAT];
            const float d = (float)min(l + 1, n);
            Cb[(size_t)l * FEAT] = __float2bfloat16(gelu_exact(s / d + bias));
        }
    }
}

// ---------------------------------------------------------------------------
extern "C" void kernel_launch(void* const* d_in, const int* in_sizes, int n_in,
                              void* d_out, int out_size, void* d_ws, size_t ws_size,
                              hipStream_t stream)
{
    const float* x  = (const float*)d_in[0];  // (B,L,512) fp32
    const float* Ws = (const float*)d_in[1];  // (512,512) fp32
    const float* bs = (const float*)d_in[2];  // (512)
    const float* Wc = (const float*)d_in[3];  // (512,512) fp32
    const float* bc = (const float*)d_in[4];  // (512)
    float* out = (float*)d_out;

    const int M = BATCH * SEQL;               // 32768

    // workspace layout: [x_bf16: 32MB][cat bf16: 32MB]
    unsigned short* x_bf = (unsigned short*)d_ws;
    __hip_bfloat16* cat  = (__hip_bfloat16*)((char*)d_ws + (size_t)M * DIM * 2);
    float* U = out;                            // fp32 scratch in d_out

    // 0) x -> bf16 (16.7M elems, 16 per thread)
    cvt_bf16<<<(M * DIM) / (256 * 16), 256, 0, stream>>>(x, x_bf);

    // 1) U = x_bf @ bf16(Ws)^T
    mfma_gemm<false><<<(M / 128) * (FEAT / 128), 256, 0, stream>>>(
        x_bf, Ws, nullptr, U, M, FEAT, DIM, FEAT / 128);

    // 2) causal window-mean + bias + exact GELU -> bf16 cat
    pool_gelu<<<dim3(SEQL / PCHUNK, BATCH), 512, 0, stream>>>(U, bs, cat);

    // 3) out = cat @ bf16(Wc)^T + bc
    mfma_gemm<true><<<(M / 128) * (OUTD / 128), 256, 0, stream>>>(
        (const unsigned short*)cat, Wc, bc, out, M, OUTD, FEAT, OUTD / 128);
}

// Round 5
// 216.110 us; speedup vs baseline: 2.7549x; 1.1313x over previous
//
#include <hip/hip_runtime.h>
#include <hip/hip_bf16.h>
#include <math.h>

// B=8, L=4096, D=512, P=128 (4 scales), O=512. M = B*L = 32768.
#define BATCH 8
#define SEQL  4096
#define DIM   512
#define FEAT  512
#define OUTD  512

typedef __attribute__((ext_vector_type(8))) short short8_t;  // 8 bf16
typedef __attribute__((ext_vector_type(4))) float f32x4;

__device__ __forceinline__ short bfbits(float f) {
    __hip_bfloat16 h = __float2bfloat16(f);
    return __builtin_bit_cast(short, h);
}
__device__ __forceinline__ short8_t pack8(float4 a, float4 b) {
    short8_t r;
    r[0] = bfbits(a.x); r[1] = bfbits(a.y); r[2] = bfbits(a.z); r[3] = bfbits(a.w);
    r[4] = bfbits(b.x); r[5] = bfbits(b.y); r[6] = bfbits(b.z); r[7] = bfbits(b.w);
    return r;
}

// async global->LDS, 16B per lane (LDS dest must be wave-uniform base + lane*16)
__device__ __forceinline__ void gload_lds16(const unsigned short* g, unsigned short* l) {
    __builtin_amdgcn_global_load_lds(
        (const __attribute__((address_space(1))) unsigned int*)g,
        (__attribute__((address_space(3))) unsigned int*)l,
        16, 0, 0);
}

// ---------- fp32 -> bf16 convert: x (blocks 0..4095), Ws (64), Wc (64) ----------
__global__ __launch_bounds__(256)
void cvt_all(const float* __restrict__ x, const float* __restrict__ Ws,
             const float* __restrict__ Wc, unsigned short* __restrict__ x_bf,
             unsigned short* __restrict__ ws_bf, unsigned short* __restrict__ wc_bf)
{
    const float* src;
    unsigned short* dst;
    size_t base;
    if (blockIdx.x < 4096)      { src = x;  dst = x_bf;  base = (size_t)blockIdx.x * 4096; }
    else if (blockIdx.x < 4160) { src = Ws; dst = ws_bf; base = (size_t)(blockIdx.x - 4096) * 4096; }
    else                        { src = Wc; dst = wc_bf; base = (size_t)(blockIdx.x - 4160) * 4096; }
    const size_t i = base / 16 + threadIdx.x;
    const float4* s = (const float4*)src + i * 4;
    float4 f0 = s[0], f1 = s[1], f2 = s[2], f3 = s[3];
    short8_t* d = (short8_t*)dst + i * 2;
    d[0] = pack8(f0, f1);
    d[1] = pack8(f2, f3);
}

// ---- bf16 MFMA GEMM, 2-phase pipelined: C[M,N] = A[M,K]*B[N,K]^T (+bias) ----
// 128x128 tile, BK=32, 4 waves (2x2), wave = 64x64 = 4x4 frags of 16x16x32.
// Both A and B bf16, staged via global_load_lds dwordx4 into double-buffered LDS.
// One __syncthreads per K-iter (implicit vmcnt0 drain = prefetch completion).
template<bool HASBIAS>
__global__ __launch_bounds__(256)
void mfma_gemm(const unsigned short* __restrict__ A, const unsigned short* __restrict__ Bw,
               const float* __restrict__ bias, float* __restrict__ C,
               int M, int N, int K, int nbx)
{
    __shared__ unsigned short As[2][128 * 32];
    __shared__ unsigned short Bs[2][128 * 32];

    // bijective XCD-chunk swizzle (gridDim.x % 8 == 0)
    const int cpx  = gridDim.x >> 3;
    const int orig = (blockIdx.x & 7) * cpx + (blockIdx.x >> 3);
    const int by = orig / nbx;
    const int bx = orig % nbx;

    const int tid  = threadIdx.x;
    const int lane = tid & 63;
    const int wave = tid >> 6;
    const int wr = wave >> 1, wc = wave & 1;
    const int fr = lane & 15, kb = lane >> 4;

    const int arow0 = by * 128;
    const int bcol0 = bx * 128;

    const int s_row = tid >> 2;           // 0..63
    const int s_col = (tid & 3) * 8;      // elem col in BK=32

    const unsigned short* Ab = A  + (size_t)(arow0 + s_row) * K + s_col;
    const unsigned short* Bb = Bw + (size_t)(bcol0 + s_row) * K + s_col;

    f32x4 acc[4][4];
#pragma unroll
    for (int m = 0; m < 4; ++m)
#pragma unroll
        for (int n = 0; n < 4; ++n) acc[m][n] = (f32x4)0.f;

    const int NT = K >> 5;

    // prologue: stage tile 0 into buf 0
    {
        gload_lds16(Ab, &As[0][tid * 8]);
        gload_lds16(Ab + (size_t)64 * K, &As[0][tid * 8 + 2048]);
        gload_lds16(Bb, &Bs[0][tid * 8]);
        gload_lds16(Bb + (size_t)64 * K, &Bs[0][tid * 8 + 2048]);
    }
    __syncthreads();   // drains vmcnt(0): tile 0 resident

    int cur = 0;
    for (int t = 0; t < NT; ++t) {
        // issue next tile's async loads into the other buffer (overlaps MFMA below)
        if (t + 1 < NT) {
            const size_t ko = (size_t)(t + 1) * 32;
            gload_lds16(Ab + ko, &As[cur ^ 1][tid * 8]);
            gload_lds16(Ab + ko + (size_t)64 * K, &As[cur ^ 1][tid * 8 + 2048]);
            gload_lds16(Bb + ko, &Bs[cur ^ 1][tid * 8]);
            gload_lds16(Bb + ko + (size_t)64 * K, &Bs[cur ^ 1][tid * 8 + 2048]);
        }

        short8_t af[4], bf_[4];
#pragma unroll
        for (int m = 0; m < 4; ++m)
            af[m] = *(const short8_t*)&As[cur][(wr * 64 + m * 16 + fr) * 32 + kb * 8];
#pragma unroll
        for (int n = 0; n < 4; ++n)
            bf_[n] = *(const short8_t*)&Bs[cur][(wc * 64 + n * 16 + fr) * 32 + kb * 8];
#pragma unroll
        for (int m = 0; m < 4; ++m)
#pragma unroll
            for (int n = 0; n < 4; ++n)
                acc[m][n] = __builtin_amdgcn_mfma_f32_16x16x32_bf16(af[m], bf_[n], acc[m][n], 0, 0, 0);

        __syncthreads();   // implicit vmcnt(0)+lgkmcnt(0): next tile resident, cur reusable
        cur ^= 1;
    }

    // epilogue: C/D layout col=lane&15, row=(lane>>4)*4+i
#pragma unroll
    for (int n = 0; n < 4; ++n) {
        const int col = bcol0 + wc * 64 + n * 16 + fr;
        const float bv = HASBIAS ? bias[col] : 0.f;
#pragma unroll
        for (int m = 0; m < 4; ++m) {
            const size_t row0 = (size_t)(arow0 + wr * 64 + m * 16 + kb * 4);
#pragma unroll
            for (int i = 0; i < 4; ++i)
                C[(row0 + i) * N + col] = acc[m][n][i] + bv;
        }
    }
}

// ------------- causal window-mean + bias + exact GELU, fp32 U -> bf16 cat -------------
#define PCHUNK 64

__device__ __forceinline__ float gelu_exact(float h) {
    return 0.5f * h * (1.f + erff(h * 0.70710678118654752f));
}

__global__ __launch_bounds__(512)
void pool_gelu(const float* __restrict__ U, const float* __restrict__ bsv,
               __hip_bfloat16* __restrict__ Cat)
{
    const int j  = threadIdx.x;            // 0..511
    const int si = j >> 7;
    const int n  = (si == 0) ? 1 : (si == 1) ? 5 : (si == 2) ? 32 : 128;
    const int b  = blockIdx.y;
    const int l0 = blockIdx.x * PCHUNK;

    const float* Ub = U + (size_t)b * SEQL * FEAT + j;
    __hip_bfloat16* Cb = Cat + (size_t)b * SEQL * FEAT + j;
    const float bias = bsv[j];

    if (n == 1) {
#pragma unroll 8
        for (int l = l0; l < l0 + PCHUNK; ++l)
            Cb[(size_t)l * FEAT] = __float2bfloat16(gelu_exact(Ub[(size_t)l * FEAT] + bias));
        return;
    }

    float s;
    {
        const int kstart = l0 - min(n, l0);
        float s0 = 0.f, s1 = 0.f, s2 = 0.f, s3 = 0.f;
        int k = kstart;
        for (; k + 4 <= l0; k += 4) {
            s0 += Ub[(size_t)(k + 0) * FEAT];
            s1 += Ub[(size_t)(k + 1) * FEAT];
            s2 += Ub[(size_t)(k + 2) * FEAT];
            s3 += Ub[(size_t)(k + 3) * FEAT];
        }
        for (; k < l0; ++k) s0 += Ub[(size_t)k * FEAT];
        s = (s0 + s1) + (s2 + s3);
    }

    if (l0 >= n) {
        const float rinv = 1.f / (float)n;
#pragma unroll 8
        for (int l = l0; l < l0 + PCHUNK; ++l) {
            s += Ub[(size_t)l * FEAT];
            s -= Ub[(size_t)(l - n) * FEAT];
            Cb[(size_t)l * FEAT] = __float2bfloat16(gelu_exact(s * rinv + bias));
        }
    } else {
        for (int l = l0; l < l0 + PCHUNK; ++l) {
            s += Ub[(size_t)l * FEAT];
            if (l >= n) s -= Ub[(size_t)(l - n) * FEAT];
            const float d = (float)min(l + 1, n);
            Cb[(size_t)l * FEAT] = __float2bfloat16(gelu_exact(s / d + bias));
        }
    }
}

// ---------------------------------------------------------------------------
extern "C" void kernel_launch(void* const* d_in, const int* in_sizes, int n_in,
                              void* d_out, int out_size, void* d_ws, size_t ws_size,
                              hipStream_t stream)
{
    const float* x  = (const float*)d_in[0];  // (B,L,512) fp32
    const float* Ws = (const float*)d_in[1];  // (512,512) fp32
    const float* bs = (const float*)d_in[2];  // (512)
    const float* Wc = (const float*)d_in[3];  // (512,512) fp32
    const float* bc = (const float*)d_in[4];  // (512)
    float* out = (float*)d_out;

    const int M = BATCH * SEQL;               // 32768

    // workspace (needs 33 MB of the 64 MB):
    //   [0,32MB):   x_bf16  -> later aliased by cat (x_bf dead after GEMM1)
    //   [32MB,+.5): Ws bf16
    //   [+.5,+1):   Wc bf16
    unsigned short* x_bf  = (unsigned short*)d_ws;
    __hip_bfloat16* cat   = (__hip_bfloat16*)d_ws;
    unsigned short* ws_bf = (unsigned short*)((char*)d_ws + ((size_t)M * DIM * 2));
    unsigned short* wc_bf = ws_bf + (size_t)FEAT * DIM;
    float* U = out;                            // fp32 scratch in d_out

    // 0) convert x, Ws, Wc to bf16
    cvt_all<<<4224, 256, 0, stream>>>(x, Ws, Wc, x_bf, ws_bf, wc_bf);

    // 1) U = x_bf @ Ws_bf^T   (pooling commutes with per-scale Linear)
    mfma_gemm<false><<<(M / 128) * (FEAT / 128), 256, 0, stream>>>(
        x_bf, ws_bf, nullptr, U, M, FEAT, DIM, FEAT / 128);

    // 2) causal window-mean + bias + exact GELU -> bf16 cat (overwrites x_bf region)
    pool_gelu<<<dim3(SEQL / PCHUNK, BATCH), 512, 0, stream>>>(U, bs, cat);

    // 3) out = cat @ Wc_bf^T + bc
    mfma_gemm<true><<<(M / 128) * (OUTD / 128), 256, 0, stream>>>(
        (const unsigned short*)cat, wc_bf, bc, out, M, OUTD, FEAT, OUTD / 128);
}

// Round 6
// 212.112 us; speedup vs baseline: 2.8068x; 1.0188x over previous
//
#include <hip/hip_runtime.h>
#include <hip/hip_bf16.h>
#include <math.h>

// B=8, L=4096, D=512, P=128 (4 scales), O=512. M = B*L = 32768.
#define BATCH 8
#define SEQL  4096
#define DIM   512
#define FEAT  512
#define OUTD  512

typedef __attribute__((ext_vector_type(8))) short short8_t;  // 8 bf16
typedef __attribute__((ext_vector_type(4))) float f32x4;

__device__ __forceinline__ short bfbits(float f) {
    __hip_bfloat16 h = __float2bfloat16(f);
    return __builtin_bit_cast(short, h);
}
__device__ __forceinline__ short8_t pack8(float4 a, float4 b) {
    short8_t r;
    r[0] = bfbits(a.x); r[1] = bfbits(a.y); r[2] = bfbits(a.z); r[3] = bfbits(a.w);
    r[4] = bfbits(b.x); r[5] = bfbits(b.y); r[6] = bfbits(b.z); r[7] = bfbits(b.w);
    return r;
}

// async global->LDS, 16B per lane (LDS dest must be wave-uniform base + lane*16)
__device__ __forceinline__ void gload_lds16(const unsigned short* g, unsigned short* l) {
    __builtin_amdgcn_global_load_lds(
        (const __attribute__((address_space(1))) unsigned int*)g,
        (__attribute__((address_space(3))) unsigned int*)l,
        16, 0, 0);
}

// ---------- fp32 -> bf16 convert: x (blocks 0..4095), Ws (64), Wc (64) ----------
__global__ __launch_bounds__(256)
void cvt_all(const float* __restrict__ x, const float* __restrict__ Ws,
             const float* __restrict__ Wc, unsigned short* __restrict__ x_bf,
             unsigned short* __restrict__ ws_bf, unsigned short* __restrict__ wc_bf)
{
    const float* src;
    unsigned short* dst;
    size_t base;
    if (blockIdx.x < 4096)      { src = x;  dst = x_bf;  base = (size_t)blockIdx.x * 4096; }
    else if (blockIdx.x < 4160) { src = Ws; dst = ws_bf; base = (size_t)(blockIdx.x - 4096) * 4096; }
    else                        { src = Wc; dst = wc_bf; base = (size_t)(blockIdx.x - 4160) * 4096; }
    const size_t i = base / 16 + threadIdx.x;
    const float4* s = (const float4*)src + i * 4;
    float4 f0 = s[0], f1 = s[1], f2 = s[2], f3 = s[3];
    short8_t* d = (short8_t*)dst + i * 2;
    d[0] = pack8(f0, f1);
    d[1] = pack8(f2, f3);
}

// ---- bf16 MFMA GEMM, 2-phase pipelined: C[M,N] = A[M,K]*B[N,K]^T (+bias) ----
// 128x128 tile, BK=32, 4 waves (2x2), wave = 64x64 = 4x4 frags of 16x16x32.
// Both A and B bf16, staged via global_load_lds dwordx4 into double-buffered LDS.
// One __syncthreads per K-iter (implicit vmcnt0 drain = prefetch completion).
template<bool HASBIAS>
__global__ __launch_bounds__(256)
void mfma_gemm(const unsigned short* __restrict__ A, const unsigned short* __restrict__ Bw,
               const float* __restrict__ bias, float* __restrict__ C,
               int M, int N, int K, int nbx)
{
    __shared__ unsigned short As[2][128 * 32];
    __shared__ unsigned short Bs[2][128 * 32];

    // bijective XCD-chunk swizzle (gridDim.x % 8 == 0)
    const int cpx  = gridDim.x >> 3;
    const int orig = (blockIdx.x & 7) * cpx + (blockIdx.x >> 3);
    const int by = orig / nbx;
    const int bx = orig % nbx;

    const int tid  = threadIdx.x;
    const int lane = tid & 63;
    const int wave = tid >> 6;
    const int wr = wave >> 1, wc = wave & 1;
    const int fr = lane & 15, kb = lane >> 4;

    const int arow0 = by * 128;
    const int bcol0 = bx * 128;

    const int s_row = tid >> 2;           // 0..63
    const int s_col = (tid & 3) * 8;      // elem col in BK=32

    const unsigned short* Ab = A  + (size_t)(arow0 + s_row) * K + s_col;
    const unsigned short* Bb = Bw + (size_t)(bcol0 + s_row) * K + s_col;

    f32x4 acc[4][4];
#pragma unroll
    for (int m = 0; m < 4; ++m)
#pragma unroll
        for (int n = 0; n < 4; ++n) acc[m][n] = (f32x4)0.f;

    const int NT = K >> 5;

    // prologue: stage tile 0 into buf 0
    {
        gload_lds16(Ab, &As[0][tid * 8]);
        gload_lds16(Ab + (size_t)64 * K, &As[0][tid * 8 + 2048]);
        gload_lds16(Bb, &Bs[0][tid * 8]);
        gload_lds16(Bb + (size_t)64 * K, &Bs[0][tid * 8 + 2048]);
    }
    __syncthreads();   // drains vmcnt(0): tile 0 resident

    int cur = 0;
    for (int t = 0; t < NT; ++t) {
        // issue next tile's async loads into the other buffer (overlaps MFMA below)
        if (t + 1 < NT) {
            const size_t ko = (size_t)(t + 1) * 32;
            gload_lds16(Ab + ko, &As[cur ^ 1][tid * 8]);
            gload_lds16(Ab + ko + (size_t)64 * K, &As[cur ^ 1][tid * 8 + 2048]);
            gload_lds16(Bb + ko, &Bs[cur ^ 1][tid * 8]);
            gload_lds16(Bb + ko + (size_t)64 * K, &Bs[cur ^ 1][tid * 8 + 2048]);
        }

        short8_t af[4], bf_[4];
#pragma unroll
        for (int m = 0; m < 4; ++m)
            af[m] = *(const short8_t*)&As[cur][(wr * 64 + m * 16 + fr) * 32 + kb * 8];
#pragma unroll
        for (int n = 0; n < 4; ++n)
            bf_[n] = *(const short8_t*)&Bs[cur][(wc * 64 + n * 16 + fr) * 32 + kb * 8];
#pragma unroll
        for (int m = 0; m < 4; ++m)
#pragma unroll
            for (int n = 0; n < 4; ++n)
                acc[m][n] = __builtin_amdgcn_mfma_f32_16x16x32_bf16(af[m], bf_[n], acc[m][n], 0, 0, 0);

        __syncthreads();   // implicit vmcnt(0)+lgkmcnt(0): next tile resident, cur reusable
        cur ^= 1;
    }

    // epilogue: C/D layout col=lane&15, row=(lane>>4)*4+i
#pragma unroll
    for (int n = 0; n < 4; ++n) {
        const int col = bcol0 + wc * 64 + n * 16 + fr;
        const float bv = HASBIAS ? bias[col] : 0.f;
#pragma unroll
        for (int m = 0; m < 4; ++m) {
            const size_t row0 = (size_t)(arow0 + wr * 64 + m * 16 + kb * 4);
#pragma unroll
            for (int i = 0; i < 4; ++i)
                C[(row0 + i) * N + col] = acc[m][n][i] + bv;
        }
    }
}

// ------------- causal window-mean + bias + exact GELU, fp32 U -> bf16 cat -------------
// PCHUNK=32: grid = (4096/32)*8 = 1024 blocks of 8 waves -> 32 waves/CU (occupancy cap),
// vs PCHUNK=64's 512 blocks / 8 waves/CU which was latency-bound at 25% occupancy.
#define PCHUNK 32

__device__ __forceinline__ float gelu_exact(float h) {
    return 0.5f * h * (1.f + erff(h * 0.70710678118654752f));
}

__global__ __launch_bounds__(512)
void pool_gelu(const float* __restrict__ U, const float* __restrict__ bsv,
               __hip_bfloat16* __restrict__ Cat)
{
    const int j  = threadIdx.x;            // 0..511
    const int si = j >> 7;
    const int n  = (si == 0) ? 1 : (si == 1) ? 5 : (si == 2) ? 32 : 128;
    const int b  = blockIdx.y;
    const int l0 = blockIdx.x * PCHUNK;

    const float* Ub = U + (size_t)b * SEQL * FEAT + j;
    __hip_bfloat16* Cb = Cat + (size_t)b * SEQL * FEAT + j;
    const float bias = bsv[j];

    if (n == 1) {
#pragma unroll 8
        for (int l = l0; l < l0 + PCHUNK; ++l)
            Cb[(size_t)l * FEAT] = __float2bfloat16(gelu_exact(Ub[(size_t)l * FEAT] + bias));
        return;
    }

    // lead-in: s = sum over [max(0,l0-n), l0), 4 accumulators for ILP
    float s;
    {
        const int kstart = l0 - min(n, l0);
        float s0 = 0.f, s1 = 0.f, s2 = 0.f, s3 = 0.f;
        int k = kstart;
        for (; k + 4 <= l0; k += 4) {
            s0 += Ub[(size_t)(k + 0) * FEAT];
            s1 += Ub[(size_t)(k + 1) * FEAT];
            s2 += Ub[(size_t)(k + 2) * FEAT];
            s3 += Ub[(size_t)(k + 3) * FEAT];
        }
        for (; k < l0; ++k) s0 += Ub[(size_t)k * FEAT];
        s = (s0 + s1) + (s2 + s3);
    }

    if (l0 >= n) {  // steady state: full window, constant denom
        const float rinv = 1.f / (float)n;
#pragma unroll 8
        for (int l = l0; l < l0 + PCHUNK; ++l) {
            s += Ub[(size_t)l * FEAT];
            s -= Ub[(size_t)(l - n) * FEAT];
            Cb[(size_t)l * FEAT] = __float2bfloat16(gelu_exact(s * rinv + bias));
        }
    } else {        // ramp (l0 < n): denom = min(l+1, n)
        for (int l = l0; l < l0 + PCHUNK; ++l) {
            s += Ub[(size_t)l * FEAT];
            if (l >= n) s -= Ub[(size_t)(l - n) * FEAT];
            const float d = (float)min(l + 1, n);
            Cb[(size_t)l * FEAT] = __float2bfloat16(gelu_exact(s / d + bias));
        }
    }
}

// ---------------------------------------------------------------------------
extern "C" void kernel_launch(void* const* d_in, const int* in_sizes, int n_in,
                              void* d_out, int out_size, void* d_ws, size_t ws_size,
                              hipStream_t stream)
{
    const float* x  = (const float*)d_in[0];  // (B,L,512) fp32
    const float* Ws = (const float*)d_in[1];  // (512,512) fp32
    const float* bs = (const float*)d_in[2];  // (512)
    const float* Wc = (const float*)d_in[3];  // (512,512) fp32
    const float* bc = (const float*)d_in[4];  // (512)
    float* out = (float*)d_out;

    const int M = BATCH * SEQL;               // 32768

    // workspace (needs 33 MB of the 64 MB):
    //   [0,32MB):   x_bf16  -> later aliased by cat (x_bf dead after GEMM1)
    //   [32MB,+.5): Ws bf16
    //   [+.5,+1):   Wc bf16
    unsigned short* x_bf  = (unsigned short*)d_ws;
    __hip_bfloat16* cat   = (__hip_bfloat16*)d_ws;
    unsigned short* ws_bf = (unsigned short*)((char*)d_ws + ((size_t)M * DIM * 2));
    unsigned short* wc_bf = ws_bf + (size_t)FEAT * DIM;
    float* U = out;                            // fp32 scratch in d_out

    // 0) convert x, Ws, Wc to bf16
    cvt_all<<<4224, 256, 0, stream>>>(x, Ws, Wc, x_bf, ws_bf, wc_bf);

    // 1) U = x_bf @ Ws_bf^T   (pooling commutes with per-scale Linear)
    mfma_gemm<false><<<(M / 128) * (FEAT / 128), 256, 0, stream>>>(
        x_bf, ws_bf, nullptr, U, M, FEAT, DIM, FEAT / 128);

    // 2) causal window-mean + bias + exact GELU -> bf16 cat (overwrites x_bf region)
    pool_gelu<<<dim3(SEQL / PCHUNK, BATCH), 512, 0, stream>>>(U, bs, cat);

    // 3) out = cat @ Wc_bf^T + bc
    mfma_gemm<true><<<(M / 128) * (OUTD / 128), 256, 0, stream>>>(
        (const unsigned short*)cat, wc_bf, bc, out, M, OUTD, FEAT, OUTD / 128);
}

// Round 7
// 209.640 us; speedup vs baseline: 2.8399x; 1.0118x over previous
//
#include <hip/hip_runtime.h>
#include <hip/hip_bf16.h>
#include <math.h>

// B=8, L=4096, D=512, P=128 (4 scales), O=512. M = B*L = 32768.
#define BATCH 8
#define SEQL  4096
#define DIM   512
#define FEAT  512
#define OUTD  512

typedef __attribute__((ext_vector_type(8))) short short8_t;  // 8 bf16
typedef __attribute__((ext_vector_type(4))) float f32x4;

__device__ __forceinline__ short bfbits(float f) {
    __hip_bfloat16 h = __float2bfloat16(f);
    return __builtin_bit_cast(short, h);
}
__device__ __forceinline__ short8_t pack8(float4 a, float4 b) {
    short8_t r;
    r[0] = bfbits(a.x); r[1] = bfbits(a.y); r[2] = bfbits(a.z); r[3] = bfbits(a.w);
    r[4] = bfbits(b.x); r[5] = bfbits(b.y); r[6] = bfbits(b.z); r[7] = bfbits(b.w);
    return r;
}

// async global->LDS, 16B per lane (LDS dest must be wave-uniform base + lane*16)
__device__ __forceinline__ void gload_lds16(const unsigned short* g, unsigned short* l) {
    __builtin_amdgcn_global_load_lds(
        (const __attribute__((address_space(1))) unsigned int*)g,
        (__attribute__((address_space(3))) unsigned int*)l,
        16, 0, 0);
}

// ---------- fp32 -> bf16 convert: x (blocks 0..4095), Ws (64), Wc (64) ----------
__global__ __launch_bounds__(256)
void cvt_all(const float* __restrict__ x, const float* __restrict__ Ws,
             const float* __restrict__ Wc, unsigned short* __restrict__ x_bf,
             unsigned short* __restrict__ ws_bf, unsigned short* __restrict__ wc_bf)
{
    const float* src;
    unsigned short* dst;
    size_t base;
    if (blockIdx.x < 4096)      { src = x;  dst = x_bf;  base = (size_t)blockIdx.x * 4096; }
    else if (blockIdx.x < 4160) { src = Ws; dst = ws_bf; base = (size_t)(blockIdx.x - 4096) * 4096; }
    else                        { src = Wc; dst = wc_bf; base = (size_t)(blockIdx.x - 4160) * 4096; }
    const size_t i = base / 16 + threadIdx.x;
    const float4* s = (const float4*)src + i * 4;
    float4 f0 = s[0], f1 = s[1], f2 = s[2], f3 = s[3];
    short8_t* d = (short8_t*)dst + i * 2;
    d[0] = pack8(f0, f1);
    d[1] = pack8(f2, f3);
}

// ---- bf16 MFMA GEMM, 3-buffer 2-deep pipeline with COUNTED vmcnt (T3+T4) ----
// 128x128 tile, BK=32, 4 waves (2x2), wave = 64x64 = 4x4 frags of 16x16x32.
// Both A and B bf16 via global_load_lds dwordx4. Raw s_barrier + exact
// s_waitcnt vmcnt(N): steady state keeps 2 tiles (8 loads/thread) in flight;
// NO vmcnt(0) drain in the main loop (the round-6 structure drained every iter).
// WAR safety: trailing barrier per iter; buf written at t+2 was last read at
// t-1, whose ds_reads are drained (MFMA lgkm dependency) before that barrier.
template<bool HASBIAS>
__global__ __launch_bounds__(256)
void mfma_gemm(const unsigned short* __restrict__ A, const unsigned short* __restrict__ Bw,
               const float* __restrict__ bias, float* __restrict__ C,
               int M, int N, int K, int nbx)
{
    __shared__ unsigned short As[3][128 * 32];
    __shared__ unsigned short Bs[3][128 * 32];

    // bijective XCD-chunk swizzle (gridDim.x % 8 == 0)
    const int cpx  = gridDim.x >> 3;
    const int orig = (blockIdx.x & 7) * cpx + (blockIdx.x >> 3);
    const int by = orig / nbx;
    const int bx = orig % nbx;

    const int tid  = threadIdx.x;
    const int lane = tid & 63;
    const int wave = tid >> 6;
    const int wr = wave >> 1, wc = wave & 1;
    const int fr = lane & 15, kb = lane >> 4;

    const int arow0 = by * 128;
    const int bcol0 = bx * 128;

    const int s_row = tid >> 2;           // 0..63
    const int s_col = (tid & 3) * 8;      // elem col in BK=32

    const unsigned short* Ab = A  + (size_t)(arow0 + s_row) * K + s_col;
    const unsigned short* Bb = Bw + (size_t)(bcol0 + s_row) * K + s_col;
    const size_t K64 = (size_t)64 * K;

    f32x4 acc[4][4];
#pragma unroll
    for (int m = 0; m < 4; ++m)
#pragma unroll
        for (int n = 0; n < 4; ++n) acc[m][n] = (f32x4)0.f;

    const int NT = K >> 5;   // 16 for K=512

    // stage tile t into buffer b (4 gload_lds per thread)
#define STAGE(t, b)  do {                                                   \
        const size_t ko_ = (size_t)(t) * 32;                                \
        gload_lds16(Ab + ko_,       &As[b][tid * 8]);                       \
        gload_lds16(Ab + ko_ + K64, &As[b][tid * 8 + 2048]);                \
        gload_lds16(Bb + ko_,       &Bs[b][tid * 8]);                       \
        gload_lds16(Bb + ko_ + K64, &Bs[b][tid * 8 + 2048]);                \
    } while (0)

#define COMPUTE(b)  do {                                                    \
        short8_t af[4], bf_[4];                                             \
        _Pragma("unroll")                                                   \
        for (int m = 0; m < 4; ++m)                                         \
            af[m] = *(const short8_t*)&As[b][(wr * 64 + m * 16 + fr) * 32 + kb * 8]; \
        _Pragma("unroll")                                                   \
        for (int n = 0; n < 4; ++n)                                         \
            bf_[n] = *(const short8_t*)&Bs[b][(wc * 64 + n * 16 + fr) * 32 + kb * 8]; \
        _Pragma("unroll")                                                   \
        for (int m = 0; m < 4; ++m)                                         \
            _Pragma("unroll")                                               \
            for (int n = 0; n < 4; ++n)                                     \
                acc[m][n] = __builtin_amdgcn_mfma_f32_16x16x32_bf16(af[m], bf_[n], acc[m][n], 0, 0, 0); \
    } while (0)

    // prologue: tiles 0,1 in flight
    STAGE(0, 0);
    STAGE(1, 1);

    int bcur = 0, bstg = 2;
    // main loop: t = 0 .. NT-3; vmcnt(8) = tiles t+1,t+2 (4 loads each) stay in flight
    for (int t = 0; t < NT - 2; ++t) {
        STAGE(t + 2, bstg);
        asm volatile("s_waitcnt vmcnt(8)" ::: "memory");
        __builtin_amdgcn_sched_barrier(0);
        __builtin_amdgcn_s_barrier();          // all waves: tile t resident in LDS
        COMPUTE(bcur);
        __builtin_amdgcn_sched_barrier(0);
        __builtin_amdgcn_s_barrier();          // all reads of tile t done -> buf reusable
        bcur = (bcur == 2) ? 0 : bcur + 1;
        bstg = (bstg == 2) ? 0 : bstg + 1;
    }
    // t = NT-2: only tile NT-1 (4 loads) may remain in flight
    asm volatile("s_waitcnt vmcnt(4)" ::: "memory");
    __builtin_amdgcn_sched_barrier(0);
    __builtin_amdgcn_s_barrier();
    COMPUTE(bcur);
    __builtin_amdgcn_sched_barrier(0);
    __builtin_amdgcn_s_barrier();
    bcur = (bcur == 2) ? 0 : bcur + 1;
    // t = NT-1: drain everything (loop is over; this is the only vmcnt(0))
    asm volatile("s_waitcnt vmcnt(0)" ::: "memory");
    __builtin_amdgcn_sched_barrier(0);
    __builtin_amdgcn_s_barrier();
    COMPUTE(bcur);

#undef STAGE
#undef COMPUTE

    // epilogue: C/D layout col=lane&15, row=(lane>>4)*4+i
#pragma unroll
    for (int n = 0; n < 4; ++n) {
        const int col = bcol0 + wc * 64 + n * 16 + fr;
        const float bv = HASBIAS ? bias[col] : 0.f;
#pragma unroll
        for (int m = 0; m < 4; ++m) {
            const size_t row0 = (size_t)(arow0 + wr * 64 + m * 16 + kb * 4);
#pragma unroll
            for (int i = 0; i < 4; ++i)
                C[(row0 + i) * N + col] = acc[m][n][i] + bv;
        }
    }
}

// ------------- causal window-mean + bias + exact GELU, fp32 U -> bf16 cat -------------
// PCHUNK=32: grid = (4096/32)*8 = 1024 blocks of 8 waves -> 32 waves/CU cap.
#define PCHUNK 32

__device__ __forceinline__ float gelu_exact(float h) {
    return 0.5f * h * (1.f + erff(h * 0.70710678118654752f));
}

__global__ __launch_bounds__(512)
void pool_gelu(const float* __restrict__ U, const float* __restrict__ bsv,
               __hip_bfloat16* __restrict__ Cat)
{
    const int j  = threadIdx.x;            // 0..511
    const int si = j >> 7;
    const int n  = (si == 0) ? 1 : (si == 1) ? 5 : (si == 2) ? 32 : 128;
    const int b  = blockIdx.y;
    const int l0 = blockIdx.x * PCHUNK;

    const float* Ub = U + (size_t)b * SEQL * FEAT + j;
    __hip_bfloat16* Cb = Cat + (size_t)b * SEQL * FEAT + j;
    const float bias = bsv[j];

    if (n == 1) {
#pragma unroll 8
        for (int l = l0; l < l0 + PCHUNK; ++l)
            Cb[(size_t)l * FEAT] = __float2bfloat16(gelu_exact(Ub[(size_t)l * FEAT] + bias));
        return;
    }

    // lead-in: s = sum over [max(0,l0-n), l0), 4 accumulators for ILP
    float s;
    {
        const int kstart = l0 - min(n, l0);
        float s0 = 0.f, s1 = 0.f, s2 = 0.f, s3 = 0.f;
        int k = kstart;
        for (; k + 4 <= l0; k += 4) {
            s0 += Ub[(size_t)(k + 0) * FEAT];
            s1 += Ub[(size_t)(k + 1) * FEAT];
            s2 += Ub[(size_t)(k + 2) * FEAT];
            s3 += Ub[(size_t)(k + 3) * FEAT];
        }
        for (; k < l0; ++k) s0 += Ub[(size_t)k * FEAT];
        s = (s0 + s1) + (s2 + s3);
    }

    if (l0 >= n) {  // steady state: full window, constant denom
        const float rinv = 1.f / (float)n;
#pragma unroll 8
        for (int l = l0; l < l0 + PCHUNK; ++l) {
            s += Ub[(size_t)l * FEAT];
            s -= Ub[(size_t)(l - n) * FEAT];
            Cb[(size_t)l * FEAT] = __float2bfloat16(gelu_exact(s * rinv + bias));
        }
    } else {        // ramp (l0 < n): denom = min(l+1, n)
        for (int l = l0; l < l0 + PCHUNK; ++l) {
            s += Ub[(size_t)l * FEAT];
            if (l >= n) s -= Ub[(size_t)(l - n) * FEAT];
            const float d = (float)min(l + 1, n);
            Cb[(size_t)l * FEAT] = __float2bfloat16(gelu_exact(s / d + bias));
        }
    }
}

// ---------------------------------------------------------------------------
extern "C" void kernel_launch(void* const* d_in, const int* in_sizes, int n_in,
                              void* d_out, int out_size, void* d_ws, size_t ws_size,
                              hipStream_t stream)
{
    const float* x  = (const float*)d_in[0];  // (B,L,512) fp32
    const float* Ws = (const float*)d_in[1];  // (512,512) fp32
    const float* bs = (const float*)d_in[2];  // (512)
    const float* Wc = (const float*)d_in[3];  // (512,512) fp32
    const float* bc = (const float*)d_in[4];  // (512)
    float* out = (float*)d_out;

    const int M = BATCH * SEQL;               // 32768

    // workspace:
    //   [0,32MB):   x_bf16  -> later aliased by cat (x_bf dead after GEMM1)
    //   [32MB,+.5): Ws bf16
    //   [+.5,+1):   Wc bf16
    unsigned short* x_bf  = (unsigned short*)d_ws;
    __hip_bfloat16* cat   = (__hip_bfloat16*)d_ws;
    unsigned short* ws_bf = (unsigned short*)((char*)d_ws + ((size_t)M * DIM * 2));
    unsigned short* wc_bf = ws_bf + (size_t)FEAT * DIM;
    float* U = out;                            // fp32 scratch in d_out

    // 0) convert x, Ws, Wc to bf16
    cvt_all<<<4224, 256, 0, stream>>>(x, Ws, Wc, x_bf, ws_bf, wc_bf);

    // 1) U = x_bf @ Ws_bf^T   (pooling commutes with per-scale Linear)
    mfma_gemm<false><<<(M / 128) * (FEAT / 128), 256, 0, stream>>>(
        x_bf, ws_bf, nullptr, U, M, FEAT, DIM, FEAT / 128);

    // 2) causal window-mean + bias + exact GELU -> bf16 cat (overwrites x_bf region)
    pool_gelu<<<dim3(SEQL / PCHUNK, BATCH), 512, 0, stream>>>(U, bs, cat);

    // 3) out = cat @ Wc_bf^T + bc
    mfma_gemm<true><<<(M / 128) * (OUTD / 128), 256, 0, stream>>>(
        (const unsigned short*)cat, wc_bf, bc, out, M, OUTD, FEAT, OUTD / 128);
}

// Round 8
// 201.320 us; speedup vs baseline: 2.9573x; 1.0413x over previous
//
#include <hip/hip_runtime.h>
#include <hip/hip_bf16.h>
#include <math.h>

// B=8, L=4096, D=512, P=128 (4 scales), O=512. M = B*L = 32768.
#define BATCH 8
#define SEQL  4096
#define DIM   512
#define FEAT  512
#define OUTD  512

typedef __attribute__((ext_vector_type(8))) short short8_t;  // 8 bf16
typedef __attribute__((ext_vector_type(4))) float f32x4;

__device__ __forceinline__ short bfbits(float f) {
    __hip_bfloat16 h = __float2bfloat16(f);
    return __builtin_bit_cast(short, h);
}
__device__ __forceinline__ short8_t pack8(float4 a, float4 b) {
    short8_t r;
    r[0] = bfbits(a.x); r[1] = bfbits(a.y); r[2] = bfbits(a.z); r[3] = bfbits(a.w);
    r[4] = bfbits(b.x); r[5] = bfbits(b.y); r[6] = bfbits(b.z); r[7] = bfbits(b.w);
    return r;
}

// async global->LDS, 16B per lane (LDS dest = wave-uniform base + lane*16, LINEAR)
__device__ __forceinline__ void gload_lds16(const unsigned short* g, unsigned short* l) {
    __builtin_amdgcn_global_load_lds(
        (const __attribute__((address_space(1))) unsigned int*)g,
        (__attribute__((address_space(3))) unsigned int*)l,
        16, 0, 0);
}

// ---------- fp32 -> bf16 convert: x (blocks 0..4095), Ws (64), Wc (64) ----------
__global__ __launch_bounds__(256)
void cvt_all(const float* __restrict__ x, const float* __restrict__ Ws,
             const float* __restrict__ Wc, unsigned short* __restrict__ x_bf,
             unsigned short* __restrict__ ws_bf, unsigned short* __restrict__ wc_bf)
{
    const float* src;
    unsigned short* dst;
    size_t base;
    if (blockIdx.x < 4096)      { src = x;  dst = x_bf;  base = (size_t)blockIdx.x * 4096; }
    else if (blockIdx.x < 4160) { src = Ws; dst = ws_bf; base = (size_t)(blockIdx.x - 4096) * 4096; }
    else                        { src = Wc; dst = wc_bf; base = (size_t)(blockIdx.x - 4160) * 4096; }
    const size_t i = base / 16 + threadIdx.x;
    const float4* s = (const float4*)src + i * 4;
    float4 f0 = s[0], f1 = s[1], f2 = s[2], f3 = s[3];
    short8_t* d = (short8_t*)dst + i * 2;
    d[0] = pack8(f0, f1);
    d[1] = pack8(f2, f3);
}

// ---- bf16 MFMA GEMM: 128x128 tile, BK=64, XOR-swizzled LDS (T2), counted vmcnt ----
// LDS tile [128 rows][64 elems] = 128B rows, 8x 16B chunks/row. Swizzle:
//   data chunk c of row R is stored at chunk slot c ^ (R&7).
// Staging: LINEAR LDS dest (gload_lds requirement) + pre-swizzled GLOBAL source
// (rule #21: both-sides-or-neither). Reads apply the same XOR -> a frag read's
// 64 lanes hit 8 distinct bank-quads = 2 lanes/bank = conflict-free (m136).
// 2 LDS bufs (64 KB -> 2 blocks/CU), 1-deep prefetch, steady-state vmcnt(8),
// only one vmcnt(0) at the final tile. NT = K/64 = 8.
template<bool HASBIAS>
__global__ __launch_bounds__(256, 2)
void mfma_gemm(const unsigned short* __restrict__ A, const unsigned short* __restrict__ Bw,
               const float* __restrict__ bias, float* __restrict__ C,
               int M, int N, int K, int nbx)
{
    __shared__ unsigned short As[2][128 * 64];
    __shared__ unsigned short Bs[2][128 * 64];

    // bijective XCD-chunk swizzle (gridDim.x % 8 == 0)
    const int cpx  = gridDim.x >> 3;
    const int orig = (blockIdx.x & 7) * cpx + (blockIdx.x >> 3);
    const int by = orig / nbx;
    const int bx = orig % nbx;

    const int tid  = threadIdx.x;
    const int lane = tid & 63;
    const int wave = tid >> 6;
    const int wr = wave >> 1, wc = wave & 1;
    const int fr = lane & 15, kb = lane >> 4;
    const int fr7 = fr & 7;

    const int arow0 = by * 128;
    const int bcol0 = bx * 128;

    // staging: pass p covers LDS bytes [p*4096 + tid*16). Linear slot ->
    // (R = p*32 + tid/8, chunk slot c' = tid&7). Source chunk c = c' ^ (R&7).
    const int s_rsub = tid >> 3;                       // 0..31
    const int s_c    = (tid & 7) ^ (s_rsub & 7);       // swizzled source chunk
    const unsigned short* Asrc[4];
    const unsigned short* Bsrc[4];
#pragma unroll
    for (int p = 0; p < 4; ++p) {
        const int R = p * 32 + s_rsub;
        Asrc[p] = A  + (size_t)(arow0 + R) * K + s_c * 8;
        Bsrc[p] = Bw + (size_t)(bcol0 + R) * K + s_c * 8;
    }

    f32x4 acc[4][4];
#pragma unroll
    for (int m = 0; m < 4; ++m)
#pragma unroll
        for (int n = 0; n < 4; ++n) acc[m][n] = (f32x4)0.f;

    const int NT = K >> 6;   // 8 for K=512

#define STAGE(t, b)  do {                                                    \
        const size_t ko_ = (size_t)(t) * 64;                                 \
        _Pragma("unroll")                                                    \
        for (int p = 0; p < 4; ++p) {                                        \
            gload_lds16(Asrc[p] + ko_, &As[b][p * 2048 + tid * 8]);          \
            gload_lds16(Bsrc[p] + ko_, &Bs[b][p * 2048 + tid * 8]);          \
        }                                                                    \
    } while (0)

    // frag reads with the same XOR: elem off = R*64 + ((ks*4+kb)^(R&7))*8
#define COMPUTE(b)  do {                                                     \
        _Pragma("unroll")                                                    \
        for (int ks = 0; ks < 2; ++ks) {                                     \
            short8_t af[4], bf_[4];                                          \
            _Pragma("unroll")                                                \
            for (int m = 0; m < 4; ++m)                                      \
                af[m] = *(const short8_t*)&As[b][(wr * 64 + m * 16 + fr) * 64 \
                         + (((ks * 4 + kb) ^ fr7) * 8)];                     \
            _Pragma("unroll")                                                \
            for (int n = 0; n < 4; ++n)                                      \
                bf_[n] = *(const short8_t*)&Bs[b][(wc * 64 + n * 16 + fr) * 64 \
                         + (((ks * 4 + kb) ^ fr7) * 8)];                     \
            _Pragma("unroll")                                                \
            for (int m = 0; m < 4; ++m)                                      \
                _Pragma("unroll")                                            \
                for (int n = 0; n < 4; ++n)                                  \
                    acc[m][n] = __builtin_amdgcn_mfma_f32_16x16x32_bf16(     \
                        af[m], bf_[n], acc[m][n], 0, 0, 0);                  \
        }                                                                    \
    } while (0)

    // prologue: tiles 0 (buf0) and 1 (buf1) in flight (16 loads/thread)
    STAGE(0, 0);
    STAGE(1, 1);

    // main loop: tile t lives in buf t&1. Order per iter:
    //   vmcnt(8)  -> tile t's 8 loads done (t+1's 8 may stay in flight)
    //   barrier   -> tile t resident for all waves
    //   COMPUTE   -> reads of buf t&1
    //   barrier   -> all waves' reads done; buf t&1 reusable
    //   STAGE t+2 -> into buf t&1 (overlaps next iter's compute)
    for (int t = 0; t < NT - 1; ++t) {
        asm volatile("s_waitcnt vmcnt(8)" ::: "memory");
        __builtin_amdgcn_sched_barrier(0);
        __builtin_amdgcn_s_barrier();
        COMPUTE(t & 1);
        __builtin_amdgcn_sched_barrier(0);
        __builtin_amdgcn_s_barrier();
        if (t + 2 < NT) STAGE(t + 2, t & 1);
    }
    // final tile: the only full drain
    asm volatile("s_waitcnt vmcnt(0)" ::: "memory");
    __builtin_amdgcn_sched_barrier(0);
    __builtin_amdgcn_s_barrier();
    COMPUTE((NT - 1) & 1);

#undef STAGE
#undef COMPUTE

    // epilogue: C/D layout col=lane&15, row=(lane>>4)*4+i
#pragma unroll
    for (int n = 0; n < 4; ++n) {
        const int col = bcol0 + wc * 64 + n * 16 + fr;
        const float bv = HASBIAS ? bias[col] : 0.f;
#pragma unroll
        for (int m = 0; m < 4; ++m) {
            const size_t row0 = (size_t)(arow0 + wr * 64 + m * 16 + kb * 4);
#pragma unroll
            for (int i = 0; i < 4; ++i)
                C[(row0 + i) * N + col] = acc[m][n][i] + bv;
        }
    }
}

// ------------- causal window-mean + bias + exact GELU, fp32 U -> bf16 cat -------------
// PCHUNK=32: grid = (4096/32)*8 = 1024 blocks of 8 waves -> 32 waves/CU cap.
#define PCHUNK 32

__device__ __forceinline__ float gelu_exact(float h) {
    return 0.5f * h * (1.f + erff(h * 0.70710678118654752f));
}

__global__ __launch_bounds__(512)
void pool_gelu(const float* __restrict__ U, const float* __restrict__ bsv,
               __hip_bfloat16* __restrict__ Cat)
{
    const int j  = threadIdx.x;            // 0..511
    const int si = j >> 7;
    const int n  = (si == 0) ? 1 : (si == 1) ? 5 : (si == 2) ? 32 : 128;
    const int b  = blockIdx.y;
    const int l0 = blockIdx.x * PCHUNK;

    const float* Ub = U + (size_t)b * SEQL * FEAT + j;
    __hip_bfloat16* Cb = Cat + (size_t)b * SEQL * FEAT + j;
    const float bias = bsv[j];

    if (n == 1) {
#pragma unroll 8
        for (int l = l0; l < l0 + PCHUNK; ++l)
            Cb[(size_t)l * FEAT] = __float2bfloat16(gelu_exact(Ub[(size_t)l * FEAT] + bias));
        return;
    }

    // lead-in: s = sum over [max(0,l0-n), l0), 4 accumulators for ILP
    float s;
    {
        const int kstart = l0 - min(n, l0);
        float s0 = 0.f, s1 = 0.f, s2 = 0.f, s3 = 0.f;
        int k = kstart;
        for (; k + 4 <= l0; k += 4) {
            s0 += Ub[(size_t)(k + 0) * FEAT];
            s1 += Ub[(size_t)(k + 1) * FEAT];
            s2 += Ub[(size_t)(k + 2) * FEAT];
            s3 += Ub[(size_t)(k + 3) * FEAT];
        }
        for (; k < l0; ++k) s0 += Ub[(size_t)k * FEAT];
        s = (s0 + s1) + (s2 + s3);
    }

    if (l0 >= n) {  // steady state: full window, constant denom
        const float rinv = 1.f / (float)n;
#pragma unroll 8
        for (int l = l0; l < l0 + PCHUNK; ++l) {
            s += Ub[(size_t)l * FEAT];
            s -= Ub[(size_t)(l - n) * FEAT];
            Cb[(size_t)l * FEAT] = __float2bfloat16(gelu_exact(s * rinv + bias));
        }
    } else {        // ramp (l0 < n): denom = min(l+1, n)
        for (int l = l0; l < l0 + PCHUNK; ++l) {
            s += Ub[(size_t)l * FEAT];
            if (l >= n) s -= Ub[(size_t)(l - n) * FEAT];
            const float d = (float)min(l + 1, n);
            Cb[(size_t)l * FEAT] = __float2bfloat16(gelu_exact(s / d + bias));
        }
    }
}

// ---------------------------------------------------------------------------
extern "C" void kernel_launch(void* const* d_in, const int* in_sizes, int n_in,
                              void* d_out, int out_size, void* d_ws, size_t ws_size,
                              hipStream_t stream)
{
    const float* x  = (const float*)d_in[0];  // (B,L,512) fp32
    const float* Ws = (const float*)d_in[1];  // (512,512) fp32
    const float* bs = (const float*)d_in[2];  // (512)
    const float* Wc = (const float*)d_in[3];  // (512,512) fp32
    const float* bc = (const float*)d_in[4];  // (512)
    float* out = (float*)d_out;

    const int M = BATCH * SEQL;               // 32768

    // workspace:
    //   [0,32MB):   x_bf16  -> later aliased by cat (x_bf dead after GEMM1)
    //   [32MB,+.5): Ws bf16
    //   [+.5,+1):   Wc bf16
    unsigned short* x_bf  = (unsigned short*)d_ws;
    __hip_bfloat16* cat   = (__hip_bfloat16*)d_ws;
    unsigned short* ws_bf = (unsigned short*)((char*)d_ws + ((size_t)M * DIM * 2));
    unsigned short* wc_bf = ws_bf + (size_t)FEAT * DIM;
    float* U = out;                            // fp32 scratch in d_out

    // 0) convert x, Ws, Wc to bf16
    cvt_all<<<4224, 256, 0, stream>>>(x, Ws, Wc, x_bf, ws_bf, wc_bf);

    // 1) U = x_bf @ Ws_bf^T   (pooling commutes with per-scale Linear)
    mfma_gemm<false><<<(M / 128) * (FEAT / 128), 256, 0, stream>>>(
        x_bf, ws_bf, nullptr, U, M, FEAT, DIM, FEAT / 128);

    // 2) causal window-mean + bias + exact GELU -> bf16 cat (overwrites x_bf region)
    pool_gelu<<<dim3(SEQL / PCHUNK, BATCH), 512, 0, stream>>>(U, bs, cat);

    // 3) out = cat @ Wc_bf^T + bc
    mfma_gemm<true><<<(M / 128) * (OUTD / 128), 256, 0, stream>>>(
        (const unsigned short*)cat, wc_bf, bc, out, M, OUTD, FEAT, OUTD / 128);
}